// Round 1
// baseline (62401.984 us; speedup 1.0000x reference)
//
#include <hip/hip_runtime.h>
#include <math.h>

// Problem dims
#define B_   128
#define S_   400
#define ENC_ 512
#define E_   256
#define H_   512
#define D_   128
#define P_   128
#define V_   30
#define T_   600

// Workspace layout (float units). Total ~53.5 MB — assumes ws_size is at least that.
#define KEYV_OFF 0
#define VALV_OFF (KEYV_OFF + B_*S_*P_)            // 6,553,600
#define H1_OFF   (VALV_OFF + B_*S_*P_)            // 13,107,200
#define C1_OFF   (H1_OFF + 2*B_*H_)
#define H2_OFF   (C1_OFF + B_*H_)
#define C2_OFF   (H2_OFF + 2*B_*D_)
#define CTX_OFF  (C2_OFF + B_*D_)
#define CHR_OFF  (CTX_OFF + B_*P_)
#define WS_FLOATS (CHR_OFF + B_)

#define PRED_N (B_*T_*V_)   // 2,304,000 floats; attention_plot follows (T_*S_ = 240,000)

__device__ __forceinline__ float sigm_(float x){ return 1.0f/(1.0f + expf(-x)); }

// ---------------- init: zero all recurrent state (ws is poisoned before timing) ---------
__global__ __launch_bounds__(256) void k_init(float* __restrict__ ws){
  const int n = WS_FLOATS - H1_OFF;
  float* p = ws + H1_OFF;
  for (int i = blockIdx.x*256 + threadIdx.x; i < n; i += gridDim.x*256) p[i] = 0.0f;
  // char buffer zeroed too: 0 bits == int 0 == SOS_TOKEN
}

// ---------------- precompute keyv/valv: [B*S,512] x [512,128] (x2) --------------------
__global__ __launch_bounds__(256) void k_kv(const float* __restrict__ enc,
    const float* __restrict__ Wk, const float* __restrict__ bk,
    const float* __restrict__ Wv, const float* __restrict__ bv,
    float* __restrict__ ws)
{
  __shared__ float As[32][68];
  __shared__ float Bs[32][68];
  const int tid = threadIdx.x;
  const int tx = tid & 15, ty = tid >> 4;
  const int n0 = blockIdx.x * 64;      // 800 n-tiles of 64 rows (B*S = 51200)
  const int c0 = blockIdx.y * 64;      // 4 col-tiles: cols 0..127 keyv, 128..255 valv
  float acc[4][4] = {};
  for (int k0 = 0; k0 < ENC_; k0 += 32){
    #pragma unroll
    for (int i = 0; i < 8; ++i){
      int idx = tid + 256*i;           // 2048 elements
      int kk = idx & 31, nl = idx >> 5;
      As[kk][nl] = enc[(size_t)(n0+nl)*ENC_ + k0 + kk];
    }
    #pragma unroll
    for (int i = 0; i < 8; ++i){
      int idx = tid + 256*i;
      int kk = idx & 31, cl = idx >> 5;
      int c = c0 + cl; int p = c & 127;
      const float* W = (c < 128) ? Wk : Wv;
      Bs[kk][cl] = W[(size_t)p*ENC_ + k0 + kk];
    }
    __syncthreads();
    #pragma unroll
    for (int kk = 0; kk < 32; ++kk){
      float4 a4 = *(const float4*)&As[kk][ty*4];
      float4 b4 = *(const float4*)&Bs[kk][tx*4];
      float aa[4] = {a4.x, a4.y, a4.z, a4.w};
      float bb[4] = {b4.x, b4.y, b4.z, b4.w};
      #pragma unroll
      for (int i=0;i<4;++i)
        #pragma unroll
        for (int j=0;j<4;++j) acc[i][j] += aa[i]*bb[j];
    }
    __syncthreads();
  }
  float* keyv = ws + KEYV_OFF;
  float* valv = ws + VALV_OFF;
  #pragma unroll
  for (int i=0;i<4;++i){
    int n = n0 + ty*4 + i; int b = n / S_; int s = n - b*S_;
    #pragma unroll
    for (int j=0;j<4;++j){
      int c = c0 + tx*4 + j;
      float v = acc[i][j];
      if (c < 128) keyv[((size_t)b*S_+s)*P_ + c]       = v + bk[c];
      else         valv[((size_t)b*S_+s)*P_ + (c-128)] = v + bv[c-128];
    }
  }
}

// ---------------- LSTM1: gates=[ce|ctx|h1]@W1^T, pointwise fused in-block -------------
// grid 256: ib=blk>>6 (4 item-groups of 32), ug=blk&63 (64 unit-groups of 8 units)
__global__ __launch_bounds__(256) void k_lstm1(
    const float* __restrict__ embed,
    const float* __restrict__ Wih1, const float* __restrict__ Whh1,
    const float* __restrict__ bih1, const float* __restrict__ bhh1,
    float* __restrict__ ws, int t)
{
  __shared__ float Xs[64][36];      // [kk][item 0..31]
  __shared__ float Wt[64][36];      // [kk][row 0..31] rows r = g*8+u
  __shared__ float red[4*1024];
  const int tid = threadIdx.x;
  const int ib = blockIdx.x >> 6;
  const int ug = blockIdx.x & 63;
  const int b0 = ib * 32;
  const float* h1old = ws + H1_OFF + (size_t)(t&1)*B_*H_;
  float*       h1new = ws + H1_OFF + (size_t)((t+1)&1)*B_*H_;
  float*       c1    = ws + C1_OFF;
  const float* ctx   = ws + CTX_OFF;
  const int*   chr   = (const int*)(ws + CHR_OFF);

  const int w = tid >> 6, lane = tid & 63;
  const int ii = lane >> 3, rg = lane & 7;   // 8 item-quads x 8 row-quads
  const int sil = tid & 31, skb = tid >> 5;  // staging roles
  const int sb  = b0 + sil;
  const int sch = chr[sb];

  float acc[4][4] = {};
  for (int k0 = 0; k0 < E_ + P_ + H_; k0 += 64){
    #pragma unroll
    for (int q = 0; q < 8; ++q){             // stage X tile
      int k = k0 + skb*8 + q;
      float v;
      if (k < 256)      v = embed[sch*E_ + k];
      else if (k < 384) v = ctx[sb*P_ + (k-256)];
      else              v = h1old[sb*H_ + (k-384)];
      Xs[skb*8+q][sil] = v;
    }
    {
      const int r = tid & 31, kb = tid >> 5; // stage W tile
      const int g = r >> 3, u = r & 7;
      const int R = g*H_ + ug*8 + u;
      #pragma unroll
      for (int q = 0; q < 8; ++q){
        int k = k0 + kb*8 + q;
        Wt[kb*8+q][r] = (k < 384) ? Wih1[(size_t)R*384 + k]
                                  : Whh1[(size_t)R*H_ + (k-384)];
      }
    }
    __syncthreads();
    #pragma unroll
    for (int kq = 0; kq < 16; ++kq){         // wave-level K split
      int kk = w*16 + kq;
      float4 xv = *(const float4*)&Xs[kk][ii*4];
      float4 wv = *(const float4*)&Wt[kk][rg*4];
      float xa[4] = {xv.x, xv.y, xv.z, xv.w};
      float wa[4] = {wv.x, wv.y, wv.z, wv.w};
      #pragma unroll
      for (int a=0;a<4;++a)
        #pragma unroll
        for (int r=0;r<4;++r) acc[a][r] += xa[a]*wa[r];
    }
    __syncthreads();
  }
  #pragma unroll
  for (int a=0;a<4;++a)
    #pragma unroll
    for (int r=0;r<4;++r)
      red[w*1024 + (ii*4+a)*32 + rg*4 + r] = acc[a][r];
  __syncthreads();
  {
    const int il = tid >> 3, u = tid & 7;    // 32 items x 8 units = 256 threads
    const int J = ug*8 + u;
    const int b = b0 + il;
    float gate[4];
    #pragma unroll
    for (int g=0; g<4; ++g){
      int o = il*32 + g*8 + u;
      gate[g] = red[o] + red[1024+o] + red[2048+o] + red[3072+o]
              + bih1[g*H_ + J] + bhh1[g*H_ + J];
    }
    float cold = c1[b*H_ + J];
    float cn = sigm_(gate[1])*cold + sigm_(gate[0])*tanhf(gate[2]);
    float hn = sigm_(gate[3])*tanhf(cn);
    c1[b*H_ + J]    = cn;
    h1new[b*H_ + J] = hn;
  }
}

// ---------------- LSTM2: gates=[h1n|h2]@W2^T --------------------------------------------
// grid 128: ib=blk>>6 (2 item-groups of 64), ug=blk&63 (64 unit-groups of 2 units)
__global__ __launch_bounds__(256) void k_lstm2(
    const float* __restrict__ Wih2, const float* __restrict__ Whh2,
    const float* __restrict__ bih2, const float* __restrict__ bhh2,
    float* __restrict__ ws, int t)
{
  __shared__ float Xs[64][68];      // [kk][item 0..63]
  __shared__ float Wt[64][12];      // [kk][row 0..7] rows r = g*2+u
  __shared__ float red[4*512];
  const int tid = threadIdx.x;
  const int ib = blockIdx.x >> 6;
  const int ug = blockIdx.x & 63;
  const int b0 = ib * 64;
  const float* h1new = ws + H1_OFF + (size_t)((t+1)&1)*B_*H_;
  const float* h2old = ws + H2_OFF + (size_t)(t&1)*B_*D_;
  float*       h2new = ws + H2_OFF + (size_t)((t+1)&1)*B_*D_;
  float*       c2    = ws + C2_OFF;

  const int w = tid >> 6, lane = tid & 63;
  const int ig2 = lane >> 2, rg2 = lane & 3; // 16 item-quads x 4 row-pairs
  float acc[4][2] = {};
  for (int k0 = 0; k0 < H_ + D_; k0 += 64){
    {
      const int il = tid & 63, kb = tid >> 6;
      const int b = b0 + il;
      #pragma unroll
      for (int q = 0; q < 16; ++q){
        int kk = kb*16 + q; int k = k0 + kk;
        Xs[kk][il] = (k < 512) ? h1new[b*H_ + k] : h2old[b*D_ + (k-512)];
      }
    }
    if (tid < 64){
      const int r = tid & 7, kb = tid >> 3;
      const int g = r >> 1, u = r & 1;
      const int R = g*D_ + ug*2 + u;         // row in [0,512)
      #pragma unroll
      for (int q=0;q<8;++q){
        int kk = kb*8+q; int k = k0+kk;
        Wt[kk][r] = (k < 512) ? Wih2[(size_t)R*H_ + k]
                              : Whh2[(size_t)R*D_ + (k-512)];
      }
    }
    __syncthreads();
    #pragma unroll
    for (int kq = 0; kq < 16; ++kq){
      int kk = w*16 + kq;
      float4 xv = *(const float4*)&Xs[kk][ig2*4];
      float2 wv = *(const float2*)&Wt[kk][rg2*2];
      acc[0][0] += xv.x*wv.x; acc[0][1] += xv.x*wv.y;
      acc[1][0] += xv.y*wv.x; acc[1][1] += xv.y*wv.y;
      acc[2][0] += xv.z*wv.x; acc[2][1] += xv.z*wv.y;
      acc[3][0] += xv.w*wv.x; acc[3][1] += xv.w*wv.y;
    }
    __syncthreads();
  }
  #pragma unroll
  for (int a=0;a<4;++a){
    red[w*512 + (ig2*4+a)*8 + rg2*2 + 0] = acc[a][0];
    red[w*512 + (ig2*4+a)*8 + rg2*2 + 1] = acc[a][1];
  }
  __syncthreads();
  if (tid < 128){
    const int il = tid >> 1, u = tid & 1;    // 64 items x 2 units
    const int J = ug*2 + u;
    const int b = b0 + il;
    float gate[4];
    #pragma unroll
    for (int g=0; g<4; ++g){
      int o = il*8 + g*2 + u;
      gate[g] = red[o] + red[512+o] + red[1024+o] + red[1536+o]
              + bih2[g*D_ + J] + bhh2[g*D_ + J];
    }
    float cold = c2[b*D_ + J];
    float cn = sigm_(gate[1])*cold + sigm_(gate[0])*tanhf(gate[2]);
    float hn = sigm_(gate[3])*tanhf(cn);
    c2[b*D_ + J]    = cn;
    h2new[b*D_ + J] = hn;
  }
}

// ---------------- attention + pred + argmax (one block per batch item) ------------------
__global__ __launch_bounds__(256) void k_attn(
    const float* __restrict__ Wq, const float* __restrict__ bq,
    const float* __restrict__ embed, const float* __restrict__ bchar,
    const int* __restrict__ lens,
    float* __restrict__ ws, float* __restrict__ out, int t)
{
  __shared__ float hs[128], qs[128], es[400], red[256], ctxs[128], oes[256], preds[30];
  const int tid = threadIdx.x;
  const int b = blockIdx.x;
  const float* h2new = ws + H2_OFF + (size_t)((t+1)&1)*B_*D_;
  const float* keyv = ws + KEYV_OFF + (size_t)b*S_*P_;
  const float* valv = ws + VALV_OFF + (size_t)b*S_*P_;
  float* ctxg = ws + CTX_OFF;
  int* chr = (int*)(ws + CHR_OFF);

  if (tid < 128) hs[tid] = h2new[b*D_ + tid];
  __syncthreads();
  if (tid < 128){                      // q[b,p] = Wq[p,:]*h2n + bq[p]
    float a = bq[tid];
    const float4* row = (const float4*)(Wq + (size_t)tid*D_);
    #pragma unroll 8
    for (int d=0; d<32; ++d){
      float4 wv = row[d];
      a += wv.x*hs[d*4] + wv.y*hs[d*4+1] + wv.z*hs[d*4+2] + wv.w*hs[d*4+3];
    }
    qs[tid] = a;
  }
  __syncthreads();
  const int len = lens[b];
  for (int s = tid; s < S_; s += 256){ // scores
    const float4* kr = (const float4*)(keyv + (size_t)s*P_);
    float a = 0.f;
    #pragma unroll 8
    for (int d=0; d<32; ++d){
      float4 kv = kr[d];
      a += kv.x*qs[d*4] + kv.y*qs[d*4+1] + kv.z*qs[d*4+2] + kv.w*qs[d*4+3];
    }
    es[s] = (s < len) ? a * 0.08838834764831845f : -1e9f;
  }
  __syncthreads();
  float m = -INFINITY;                 // row max
  for (int s = tid; s < S_; s += 256) m = fmaxf(m, es[s]);
  red[tid] = m; __syncthreads();
  for (int o = 128; o > 0; o >>= 1){ if (tid < o) red[tid] = fmaxf(red[tid], red[tid+o]); __syncthreads(); }
  m = red[0]; __syncthreads();
  float psum = 0.f;                    // exp + sum
  for (int s = tid; s < S_; s += 256){ float p = expf(es[s]-m); es[s] = p; psum += p; }
  red[tid] = psum; __syncthreads();
  for (int o = 128; o > 0; o >>= 1){ if (tid < o) red[tid] += red[tid+o]; __syncthreads(); }
  const float sum = red[0]; __syncthreads();
  {                                    // ctx[p] = (sum_s exp_s * valv[s,p]) / sum
    const int p = tid & 127, half = tid >> 7;
    float a = 0.f;
    const float* vp = valv + p;
    #pragma unroll 4
    for (int s = half*200; s < half*200+200; ++s) a += es[s] * vp[(size_t)s*P_];
    red[tid] = a;
  }
  __syncthreads();
  if (tid < 128){
    float c = (red[tid] + red[tid+128]) / sum;
    ctxs[tid] = c;
    ctxg[b*P_ + tid] = c;
    oes[tid] = qs[tid]; oes[128+tid] = c;
  }
  __syncthreads();
  {                                    // pred[v] = [q|ctx] . embed[v] + b_char[v]
    const int v = tid >> 3, k8 = tid & 7;
    float a = 0.f;
    if (v < V_){
      const float* er = embed + (size_t)v*E_ + k8*32;
      const float* oe = oes + k8*32;
      #pragma unroll
      for (int k=0;k<32;++k) a += er[k]*oe[k];
    }
    a += __shfl_down(a, 4, 8);
    a += __shfl_down(a, 2, 8);
    a += __shfl_down(a, 1, 8);
    if (v < V_ && k8 == 0){
      float pv = a + bchar[v];
      preds[v] = pv;
      out[((size_t)b*T_ + t)*V_ + v] = pv;
    }
  }
  __syncthreads();
  if (tid < 32){                       // argmax, first-index tie-break (numpy semantics)
    float val = (tid < V_) ? preds[tid] : -INFINITY;
    int idx = tid;
    #pragma unroll
    for (int o = 16; o > 0; o >>= 1){
      float ov = __shfl_down(val, o, 32);
      int oi = __shfl_down(idx, o, 32);
      if (ov > val || (ov == val && oi < idx)){ val = ov; idx = oi; }
    }
    if (tid == 0) chr[b] = idx;
  }
  if (b == 0){                         // attention_plot row for item 0
    for (int s = tid; s < S_; s += 256) out[PRED_N + (size_t)t*S_ + s] = es[s]/sum;
  }
}

extern "C" void kernel_launch(void* const* d_in, const int* in_sizes, int n_in,
                              void* d_out, int out_size, void* d_ws, size_t ws_size,
                              hipStream_t stream)
{
  (void)in_sizes; (void)n_in; (void)out_size; (void)ws_size; // needs ~53.5MB ws
  const float* enc   = (const float*)d_in[0];
  const int*   lens  = (const int*)d_in[1];
  const float* embed = (const float*)d_in[2];
  const float* Wih1  = (const float*)d_in[3];
  const float* Whh1  = (const float*)d_in[4];
  const float* bih1  = (const float*)d_in[5];
  const float* bhh1  = (const float*)d_in[6];
  const float* Wih2  = (const float*)d_in[7];
  const float* Whh2  = (const float*)d_in[8];
  const float* bih2  = (const float*)d_in[9];
  const float* bhh2  = (const float*)d_in[10];
  const float* Wk    = (const float*)d_in[11];
  const float* bk    = (const float*)d_in[12];
  const float* Wv    = (const float*)d_in[13];
  const float* bv    = (const float*)d_in[14];
  const float* Wq    = (const float*)d_in[15];
  const float* bq    = (const float*)d_in[16];
  const float* bchar = (const float*)d_in[17];
  float* out = (float*)d_out;
  float* ws  = (float*)d_ws;

  hipLaunchKernelGGL(k_init, dim3(256), dim3(256), 0, stream, ws);
  hipLaunchKernelGGL(k_kv, dim3(800,4), dim3(256), 0, stream, enc, Wk, bk, Wv, bv, ws);
  for (int t = 0; t < T_; ++t){
    hipLaunchKernelGGL(k_lstm1, dim3(256), dim3(256), 0, stream,
                       embed, Wih1, Whh1, bih1, bhh1, ws, t);
    hipLaunchKernelGGL(k_lstm2, dim3(128), dim3(256), 0, stream,
                       Wih2, Whh2, bih2, bhh2, ws, t);
    hipLaunchKernelGGL(k_attn, dim3(128), dim3(256), 0, stream,
                       Wq, bq, embed, bchar, lens, ws, out, t);
  }
}